// Round 9
// baseline (477.654 us; speedup 1.0000x reference)
//
#include <hip/hip_runtime.h>
#include <hip/hip_fp16.h>
#include <hip/hip_cooperative_groups.h>

namespace cg = cooperative_groups;

// CapsuleLayer dynamic routing — round 9: ONE cooperative kernel.
// Empirical law from R3-R8: round_time ~ 29us + 6us*(blocks/CU), independent
// of inner-loop content -> the walls are per-block turnaround at ~1 resident
// block/CU and per-dispatch fixed cost (ramp + cold X/W re-stream each round).
// Fix: grid = 256 blocks x 640 thr (exactly 1/CU), each block owns (bg, 9
// Gp-tiles); rounds separated by cg::grid().sync() instead of kernel
// boundaries; W/X software-pipelined across tiles (L2-warm for rounds 1-2);
// bias+softmax(bias) cached in LDS; squash fused into the kernel tail.
// 2 dispatches total (prep + main).

#define IC 1152
#define IE 8
#define NC 10
#define DV 16
#define NB 256
#define NW (IC * NC * IE * DV)  // 1,474,560
#define BT 4                    // batch elements per block
#define TPB 640                 // wave w <-> output capsule j=w
#define SOUT (NC * DV)          // 160
#define SB (NB * SOUT)          // 40,960 floats per s buffer
#define NT 9                    // tiles (Gp) per block
#define ROWS (NT * 32)          // 288 i-rows per block

typedef _Float16 h2 __attribute__((ext_vector_type(2)));
union WChunk { int4 v; h2 p[4]; _Float16 h[8]; };

static __device__ inline float fdot2f(h2 a, h2 b, float c) {
#if defined(__has_builtin) && __has_builtin(__builtin_amdgcn_fdot2)
    return __builtin_amdgcn_fdot2(a, b, c, false);
#else
    return fmaf((float)a.x, (float)b.x, fmaf((float)a.y, (float)b.y, c));
#endif
}

static __device__ inline h2 pkrtz(float a, float b) {
#if defined(__has_builtin) && __has_builtin(__builtin_amdgcn_cvt_pkrtz)
    return __builtin_bit_cast(h2, __builtin_amdgcn_cvt_pkrtz(a, b));
#else
    return h2{(_Float16)a, (_Float16)b};
#endif
}

// prep: W fp32 [i][j][e][d] -> fp16 chunks Wc[((Gp*10+j)*8+k)*64 + lane]
// (lane = h*32+r, i = Gp*32+r, d = h*8+k; chunk = e=0..7 of W[i,j,:,d]),
// PLUS zero the three s accumulator buffers (ws is poisoned every launch).
__global__ void prep_kernel(const float* __restrict__ W, int4* __restrict__ Wc,
                            float4* __restrict__ sz) {
    const int t = blockIdx.x * blockDim.x + threadIdx.x;
    if (t < 3 * SB / 4) sz[t] = make_float4(0.f, 0.f, 0.f, 0.f);
    if (t >= NW / 8) return;
    const int lane = t & 63;
    const int h = lane >> 5, r = lane & 31;
    const int k = (t >> 6) & 7;
    const int r2 = t >> 9;  // Gp*10 + j
    const int j = r2 % NC, Gp = r2 / NC;
    const int i = Gp * 32 + r;
    const int d = h * 8 + k;
    const float* src = W + ((size_t)(i * NC + j) * IE) * DV + d;  // e-stride DV
    WChunk c;
#pragma unroll
    for (int e = 0; e < IE; ++e) c.h[e] = (_Float16)src[(size_t)e * DV];
    Wc[t] = c.v;
}

struct Tile {
    WChunk w[8];   // 32 VGPR: this (j, h-half)'s W fragment for 32 rows
    h2 xh[BT][4];  // 16 VGPR: X rows for 4 batch elements, packed fp16
};

static __device__ inline void load_tile(Tile& T, const int4* __restrict__ Wc,
                                        const float* __restrict__ X, int gq, int tt,
                                        int bg, int j, int g) {
    const int Gp = gq * NT + tt;
    const int i = Gp * 32 + (g & 31);
    const int4* wp = Wc + ((size_t)(Gp * NC + j) * 8) * 64 + g;
#pragma unroll
    for (int k = 0; k < 8; ++k) T.w[k].v = wp[k * 64];
#pragma unroll
    for (int bi = 0; bi < BT; ++bi) {
        const int b = bg * BT + bi;
        const float4* xr = (const float4*)(X + ((size_t)b * IC + i) * IE);
        float4 x0 = xr[0], x1 = xr[1];
        T.xh[bi][0] = pkrtz(x0.x, x0.y);
        T.xh[bi][1] = pkrtz(x0.z, x0.w);
        T.xh[bi][2] = pkrtz(x1.x, x1.y);
        T.xh[bi][3] = pkrtz(x1.z, x1.w);
    }
}

__global__ __launch_bounds__(TPB, 3) void caps_main(
    const float* __restrict__ X,     // [B, IC, IE] fp32
    const int4* __restrict__ Wc,     // coalesced fp16 W
    const float* __restrict__ bias,  // [IC*NC] fp32
    float* __restrict__ s0,          // [B*160] round-0 s (pre-zeroed)
    float* __restrict__ s1,          // round-1 s
    float* __restrict__ s2,          // round-2 s
    float* __restrict__ out)         // [B, NC, DV] fp32
{
    __shared__ float bias_lds[ROWS * NC];  // 11.5 KB: logit bias rows
    __shared__ float c0_lds[ROWS * NC];    // 11.5 KB: softmax(bias) (round 0 c)
    __shared__ float vA[BT * SOUT];        // v1 (r1) / v1+v2 (r2)
    __shared__ float s_lds[BT * SOUT];     // block-local s accumulator
    __shared__ float Zb[3][32];            // triple-buffered per-row sum(exp)

    cg::grid_group gridg = cg::this_grid();

    const int bid = blockIdx.x;
    const int bg = bid & 63;   // batch group: b = bg*4 + bi
    const int gq = bid >> 6;   // Gp quarter: Gp = gq*9 + tt
    const int tid = threadIdx.x;
    const int j = tid >> 6;    // wave = output capsule
    const int g = tid & 63;
    const int h = g >> 5;      // d-half
    const int r = g & 31;      // row within tile

    // ---- once: bias rows + c0 = softmax(bias) into LDS ----
    if (tid < ROWS) {
        const int i = gq * ROWS + tid;
        const float2* bp = (const float2*)(bias + (size_t)i * NC);
        float b10[NC];
#pragma unroll
        for (int q = 0; q < 5; ++q) {
            float2 t2 = bp[q];
            b10[2 * q] = t2.x;
            b10[2 * q + 1] = t2.y;
        }
        float Z = 0.f, e10[NC];
#pragma unroll
        for (int jj = 0; jj < NC; ++jj) {
            e10[jj] = __expf(b10[jj]);
            Z += e10[jj];
        }
        const float rz = __builtin_amdgcn_rcpf(Z);
#pragma unroll
        for (int jj = 0; jj < NC; ++jj) {
            bias_lds[tid * NC + jj] = b10[jj];
            c0_lds[tid * NC + jj] = e10[jj] * rz;
        }
    }

    for (int rnd = 0; rnd < 3; ++rnd) {
        if (rnd >= 1) {
            __threadfence();
            gridg.sync();  // all s_glob[rnd-1] atomics visible
            // fused squash: vA = squash(s0) (+ squash(s1) for rnd 2)
            if (tid < BT * 20) {
                const int bi = tid / 20, rem = tid - bi * 20;
                const int jj = rem >> 1, hh = rem & 1;
                const int b = bg * BT + bi;
                const float4* sp = (const float4*)(s0 + (size_t)b * SOUT + jj * DV + hh * 8);
                float4 a0 = sp[0], a1 = sp[1];
                float s8[8] = {a0.x, a0.y, a0.z, a0.w, a1.x, a1.y, a1.z, a1.w};
                float sq = 0.f;
#pragma unroll
                for (int k = 0; k < 8; ++k) sq = fmaf(s8[k], s8[k], sq);
                float sqf = sq + __shfl_xor(sq, 1);
                float sc = sqrtf(sqf) / (1.f + sqf);
                float v8[8];
#pragma unroll
                for (int k = 0; k < 8; ++k) v8[k] = sc * s8[k];
                if (rnd == 2) {
                    const float4* tp = (const float4*)(s1 + (size_t)b * SOUT + jj * DV + hh * 8);
                    float4 b0 = tp[0], b1 = tp[1];
                    float t8[8] = {b0.x, b0.y, b0.z, b0.w, b1.x, b1.y, b1.z, b1.w};
                    float tq = 0.f;
#pragma unroll
                    for (int k = 0; k < 8; ++k) tq = fmaf(t8[k], t8[k], tq);
                    float tqf = tq + __shfl_xor(tq, 1);
                    float tsc = sqrtf(tqf) / (1.f + tqf);
#pragma unroll
                    for (int k = 0; k < 8; ++k) v8[k] = fmaf(tsc, t8[k], v8[k]);
                }
#pragma unroll
                for (int k = 0; k < 8; ++k) vA[bi * SOUT + jj * DV + hh * 8 + k] = v8[k];
            }
        }
        s_lds[tid] = 0.f;
        if (tid < 96) ((float*)Zb)[tid] = 0.f;
        __syncthreads();  // vA/c0/s_lds/Zb ready

        Tile TA, TB;
        load_tile(TA, Wc, X, gq, 0, bg, j, g);

        for (int tt = 0; tt < NT; ++tt) {
            if (tt < NT - 1) load_tile(TB, Wc, X, gq, tt + 1, bg, j, g);  // pipeline

            const int rr = tt * 32 + r;
            const float ltb = bias_lds[rr * NC + j];
            const float c0t = c0_lds[rr * NC + j];

            for (int bi = 0; bi < BT; ++bi) {
                float hat[8];
#pragma unroll
                for (int k = 0; k < 8; ++k) {
                    float a = 0.f;
#pragma unroll
                    for (int q = 0; q < 4; ++q) a = fdot2f(TA.xh[bi][q], TA.w[k].p[q], a);
                    hat[k] = a;
                }

                float c;
                if (rnd >= 1) {
                    const float4* vp = (const float4*)&vA[bi * SOUT + j * DV + h * 8];
                    float4 va = vp[0], vb = vp[1];
                    const float vv[8] = {va.x, va.y, va.z, va.w, vb.x, vb.y, vb.z, vb.w};
                    float ah = 0.f;
#pragma unroll
                    for (int k = 0; k < 8; ++k) ah = fmaf(hat[k], vv[k], ah);
                    const float lt = ltb + ah + __shfl_xor(ah, 32);
                    const float ex = __expf(lt);
                    const int q = tt * BT + bi;  // global bi counter for Zb rotation
                    if (h == 0) atomicAdd(&Zb[q % 3][r], ex);
                    if (tid >= 64 && tid < 96) Zb[(q + 1) % 3][tid & 31] = 0.f;
                    __syncthreads();
                    c = ex * __builtin_amdgcn_rcpf(Zb[q % 3][r]);
                } else {
                    c = c0t;  // no barrier, no DS
                }

                float s8[8];
#pragma unroll
                for (int k = 0; k < 8; ++k) s8[k] = c * hat[k];

                // octet splitting butterfly over 8 r-lanes -> lane holds k=(r&7)
                float t4[4];
#pragma unroll
                for (int m = 0; m < 4; ++m) {
                    const bool hi = (r & 4) != 0;
                    float mine = hi ? s8[m + 4] : s8[m];
                    float send = hi ? s8[m] : s8[m + 4];
                    t4[m] = mine + __shfl_xor(send, 4);
                }
                float t2[2];
#pragma unroll
                for (int m = 0; m < 2; ++m) {
                    const bool hi = (r & 2) != 0;
                    float mine = hi ? t4[m + 2] : t4[m];
                    float send = hi ? t4[m] : t4[m + 2];
                    t2[m] = mine + __shfl_xor(send, 2);
                }
                float t1;
                {
                    const bool hi = (r & 1) != 0;
                    float mine = hi ? t2[1] : t2[0];
                    float send = hi ? t2[0] : t2[1];
                    t1 = mine + __shfl_xor(send, 1);
                }
                atomicAdd(&s_lds[bi * SOUT + j * DV + h * 8 + (r & 7)], t1);
            }

            if (tt < NT - 1) TA = TB;
        }

        __syncthreads();
        // one global atomic per thread; per (b,slot) contended by 4 gq-blocks
        float* sg = (rnd == 0) ? s0 : (rnd == 1 ? s1 : s2);
        const int bo = tid / SOUT, slot = tid % SOUT;
        atomicAdd(&sg[(size_t)(bg * BT + bo) * SOUT + slot], s_lds[tid]);
    }

    __threadfence();
    gridg.sync();  // s2 complete

    // fused final squash -> out (first 64 blocks, 160 threads each)
    if (gq == 0 && tid < SOUT) {
#pragma unroll
        for (int bo = 0; bo < BT; ++bo) {
            const int b = bg * BT + bo;
            float sv = s2[(size_t)b * SOUT + tid];
            float sq = sv * sv;
#pragma unroll
            for (int mk = 8; mk >= 1; mk >>= 1) sq += __shfl_xor(sq, mk, 16);
            float sc = sqrtf(sq) / (1.f + sq);
            out[(size_t)b * SOUT + tid] = sc * sv;
        }
    }
}

extern "C" void kernel_launch(void* const* d_in, const int* in_sizes, int n_in,
                              void* d_out, int out_size, void* d_ws, size_t ws_size,
                              hipStream_t stream) {
    const float* X = (const float*)d_in[0];     // [256,1152,8]
    const float* W = (const float*)d_in[1];     // [1152,10,8,16]
    const float* bias = (const float*)d_in[2];  // [1,1152,10]
    float* out = (float*)d_out;

    // ws (floats): Wc (NW/2) | s0 | s1 | s2   = ~3.4 MB
    float* base = (float*)d_ws;
    int4* Wc = (int4*)d_ws;
    float* s0 = base + NW / 2;
    float* s1 = s0 + SB;
    float* s2 = s1 + SB;

    prep_kernel<<<dim3(720), dim3(256), 0, stream>>>(W, Wc, (float4*)s0);

    void* args[] = {(void*)&X, (void*)&Wc, (void*)&bias,
                    (void*)&s0, (void*)&s1, (void*)&s2, (void*)&out};
    hipLaunchCooperativeKernel((const void*)caps_main, dim3(NB), dim3(TPB),
                               args, 0, stream);
}